// Round 5
// baseline (566.324 us; speedup 1.0000x reference)
//
#include <hip/hip_runtime.h>
#include <hip/hip_bf16.h>
#include <cstdint>
#include <cstddef>

#define NN 50000
#define RR 4
#define EE 400000
#define TE (RR*EE)
#define HB 6250          // bins per range (8 ranges * 6250 = 50000)
#define RN (RR*NN)       // 200000
#define NSEG (NN*RR)     // 200000 (d-major, r-minor segments)
#define SCB2 782         // ceil(NSEG/256)

using frag_ab = __attribute__((ext_vector_type(8))) short;   // 8 bf16 (4 VGPRs)
using frag_cd = __attribute__((ext_vector_type(4))) float;   // 4 fp32

static __device__ __forceinline__ unsigned short f2bf(float f) {
    union { float f; unsigned u; } v; v.f = f;
    unsigned r = (v.u + 0x7FFF + ((v.u >> 16) & 1)) >> 16;   // RNE
    return (unsigned short)r;
}
static __device__ __forceinline__ unsigned pack2(float lo, float hi) {
    return (unsigned)f2bf(lo) | ((unsigned)f2bf(hi) << 16);
}

// ---------------- degree histograms: 256 blocks, zero global atomics ----------------
// bid: combo = bid>>5 (r*2+side), quarter = (bid>>3)&3, range = bid&7
// Each block scans one quarter of one relation's src or dst array and
// histograms its range into LDS, storing to a per-quarter count array.
__global__ __launch_bounds__(1024) void k_hist(const int* __restrict__ src,
                                               const int* __restrict__ dst,
                                               int* __restrict__ cnt_srcQ,
                                               int* __restrict__ cnt_dstQ) {
    __shared__ int bins[HB];
    int combo = blockIdx.x >> 5;
    int q     = (blockIdx.x >> 3) & 3;
    int range = blockIdx.x & 7;
    int r = combo >> 1;
    int side = combo & 1;
    const int* arr = (side == 0 ? src : dst) + (size_t)r * EE + (size_t)q * (EE / 4);
    int lo = range * HB;
    for (int i = threadIdx.x; i < HB; i += 1024) bins[i] = 0;
    __syncthreads();
    const int4* a4 = (const int4*)arr;
    for (int i = threadIdx.x; i < EE / 16; i += 1024) {   // EE/4 ints = EE/16 int4
        int4 v = a4[i];
        int t;
        t = v.x - lo; if ((unsigned)t < (unsigned)HB) atomicAdd(&bins[t], 1);
        t = v.y - lo; if ((unsigned)t < (unsigned)HB) atomicAdd(&bins[t], 1);
        t = v.z - lo; if ((unsigned)t < (unsigned)HB) atomicAdd(&bins[t], 1);
        t = v.w - lo; if ((unsigned)t < (unsigned)HB) atomicAdd(&bins[t], 1);
    }
    __syncthreads();
    int* outp = (side == 0 ? cnt_srcQ : cnt_dstQ) + (size_t)q * RN + (size_t)r * NN + lo;
    for (int i = threadIdx.x; i < HB; i += 1024) outp[i] = bins[i];
}

// sum quarters -> norms (fp32, [r*NN+d] layout) + counts in [d*4+r] layout for the scan
__global__ __launch_bounds__(256) void k_sum_norms(const int* __restrict__ cnt_srcQ,
                                                   const int* __restrict__ cnt_dstQ,
                                                   float* __restrict__ nsrc,
                                                   float* __restrict__ ndst,
                                                   int* __restrict__ cntd2) {
    int i = blockIdx.x * 256 + threadIdx.x;
    if (i >= RN) return;
    int ss = cnt_srcQ[i] + cnt_srcQ[RN + i] + cnt_srcQ[2 * RN + i] + cnt_srcQ[3 * RN + i];
    int ds = cnt_dstQ[i] + cnt_dstQ[RN + i] + cnt_dstQ[2 * RN + i] + cnt_dstQ[3 * RN + i];
    nsrc[i] = 1.0f / sqrtf(fmaxf((float)ss, 1.0f));
    ndst[i] = 1.0f / sqrtf(fmaxf((float)ds, 1.0f));
    int r = i / NN, d = i - r * NN;
    cntd2[d * 4 + r] = ds;
}

// ---------------- 3-phase parallel scan over 200K (d,r) segment counts ----------------
__global__ __launch_bounds__(256) void k_partial(const int* __restrict__ cntd2,
                                                 int* __restrict__ part) {
    __shared__ int s[256];
    int t = threadIdx.x;
    int f = blockIdx.x * 256 + t;
    int v = (f < NSEG) ? cntd2[f] : 0;
    s[t] = v;
    __syncthreads();
    for (int off = 128; off > 0; off >>= 1) {
        if (t < off) s[t] += s[t + off];
        __syncthreads();
    }
    if (t == 0) part[blockIdx.x] = s[0];
}

__global__ __launch_bounds__(1024) void k_scan_small(const int* __restrict__ part,
                                                     int* __restrict__ offs) {
    __shared__ int s[1024];
    int t = threadIdx.x;
    s[t] = (t < SCB2) ? part[t] : 0;
    __syncthreads();
    for (int off = 1; off < 1024; off <<= 1) {
        int v = (t >= off) ? s[t - off] : 0;
        __syncthreads();
        s[t] += v;
        __syncthreads();
    }
    if (t < SCB2) offs[t] = (t == 0) ? 0 : s[t - 1];
}

__global__ __launch_bounds__(256) void k_emit(const int* __restrict__ cntd2,
                                              const int* __restrict__ offs,
                                              int* __restrict__ rp2,
                                              int* __restrict__ cursor2) {
    __shared__ int s[256];
    int t = threadIdx.x;
    int f = blockIdx.x * 256 + t;
    int v = (f < NSEG) ? cntd2[f] : 0;
    s[t] = v;
    __syncthreads();
    for (int off = 1; off < 256; off <<= 1) {
        int u = (t >= off) ? s[t - off] : 0;
        __syncthreads();
        s[t] += u;
        __syncthreads();
    }
    if (f < NSEG) {
        int ex = offs[blockIdx.x] + s[t] - v;
        rp2[f] = ex;
        cursor2[f] = ex;
    }
    if (f == NSEG - 1) rp2[NSEG] = TE;
}

// fill CSR: edges store ONLY src as ushort (r implied by segment, w recomputed in agg)
__global__ __launch_bounds__(256) void k_fill(const int* __restrict__ src,
                                              const int* __restrict__ dst,
                                              int* __restrict__ cursor2,
                                              unsigned short* __restrict__ eb) {
    int i = blockIdx.x * 256 + threadIdx.x;
    if (i >= EE) return;
    int r = blockIdx.y;
    int idx = r * EE + i;
    int s = src[idx], d = dst[idx];
    int pos = atomicAdd(&cursor2[d * 4 + r], 1);
    eb[pos] = (unsigned short)s;
}

// ---------------- converts ----------------
__global__ __launch_bounds__(256) void k_cvt_x(const float4* __restrict__ x4,
                                               uint2* __restrict__ o, int n4) {
    int i = blockIdx.x * 256 + threadIdx.x;
    if (i >= n4) return;
    float4 v = x4[i];
    o[i] = make_uint2(pack2(v.x, v.y), pack2(v.z, v.w));
}

// Bt[n][k] = bf16(basis[k][n]); basis flat [256][BN]
__global__ __launch_bounds__(256) void k_cvt_bt(const float* __restrict__ B,
                                                unsigned short* __restrict__ Bt, int BN) {
    int o = blockIdx.x * 256 + threadIdx.x;
    if (o >= BN * 256) return;
    int k = o & 255, n = o >> 8;
    Bt[o] = f2bf(B[k * BN + n]);
}

// ---------------- aggregation: one wave per dst node, half-wave per edge ----------------
// hb2: bf16 rows of 128 ch = 32 uint2. Per (d,r) segment: constants uniform.
// Each half-wave (32 lanes x uint2) covers one full 256B row per edge.
__global__ __launch_bounds__(256) void k_agg(const uint2* __restrict__ hb2,
                                             const int* __restrict__ rp2,
                                             const unsigned short* __restrict__ eb,
                                             const float* __restrict__ nsrc,
                                             const float* __restrict__ ndst,
                                             const float* __restrict__ coeff,
                                             uint2* __restrict__ Mb2) {
    int wave = (blockIdx.x * 256 + threadIdx.x) >> 6;
    int lane = threadIdx.x & 63;
    if (wave >= NN) return;
    int half = lane >> 5, hl = lane & 31;

    float acc[8];
#pragma unroll
    for (int i = 0; i < 8; i++) acc[i] = 0.f;

    int4 seg = *(const int4*)&rp2[wave * 4];
    int bounds[5] = {seg.x, seg.y, seg.z, seg.w, rp2[wave * 4 + 4]};

#pragma unroll
    for (int r = 0; r < RR; r++) {
        int e0 = bounds[r], e1 = bounds[r + 1];
        if (e0 >= e1) continue;
        float nd = ndst[r * NN + wave];
        float cA = coeff[r * 2 + 0] * nd;
        float cB = coeff[r * 2 + 1] * nd;

        int e = e0;
        // 2 pairs (4 edges) per iteration: keeps 2 dependent gathers in flight per half
        for (; e + 3 < e1; e += 4) {
            int sA = eb[e + half];
            int sB = eb[e + 2 + half];
            float nsA = nsrc[r * NN + sA];
            float nsB = nsrc[r * NN + sB];
            uint2 hvA = hb2[(size_t)sA * 32 + hl];
            uint2 hvB = hb2[(size_t)sB * 32 + hl];
            float wA0 = cA * nsA, wA1 = cB * nsA;
            float wB0 = cA * nsB, wB1 = cB * nsB;
            float a0 = __uint_as_float(hvA.x << 16);
            float a1 = __uint_as_float(hvA.x & 0xFFFF0000u);
            float a2 = __uint_as_float(hvA.y << 16);
            float a3 = __uint_as_float(hvA.y & 0xFFFF0000u);
            acc[0] += wA0 * a0; acc[1] += wA0 * a1; acc[2] += wA0 * a2; acc[3] += wA0 * a3;
            acc[4] += wA1 * a0; acc[5] += wA1 * a1; acc[6] += wA1 * a2; acc[7] += wA1 * a3;
            float b0 = __uint_as_float(hvB.x << 16);
            float b1 = __uint_as_float(hvB.x & 0xFFFF0000u);
            float b2 = __uint_as_float(hvB.y << 16);
            float b3 = __uint_as_float(hvB.y & 0xFFFF0000u);
            acc[0] += wB0 * b0; acc[1] += wB0 * b1; acc[2] += wB0 * b2; acc[3] += wB0 * b3;
            acc[4] += wB1 * b0; acc[5] += wB1 * b1; acc[6] += wB1 * b2; acc[7] += wB1 * b3;
        }
        for (; e < e1; e += 2) {
            int ee = e + half;
            if (ee < e1) {
                int s = eb[ee];
                float ns = nsrc[r * NN + s];
                uint2 hv = hb2[(size_t)s * 32 + hl];
                float w0 = cA * ns, w1 = cB * ns;
                float a0 = __uint_as_float(hv.x << 16);
                float a1 = __uint_as_float(hv.x & 0xFFFF0000u);
                float a2 = __uint_as_float(hv.y << 16);
                float a3 = __uint_as_float(hv.y & 0xFFFF0000u);
                acc[0] += w0 * a0; acc[1] += w0 * a1; acc[2] += w0 * a2; acc[3] += w0 * a3;
                acc[4] += w1 * a0; acc[5] += w1 * a1; acc[6] += w1 * a2; acc[7] += w1 * a3;
            }
        }
    }

    // cross-half reduce: both halves end with full sums
#pragma unroll
    for (int i = 0; i < 8; i++) acc[i] += __shfl_xor(acc[i], 32, 64);

    // half 0 stores c0-output channels (0..127), half 1 stores c1-output (128..255)
    float v0 = half ? acc[4] : acc[0];
    float v1 = half ? acc[5] : acc[1];
    float v2 = half ? acc[6] : acc[2];
    float v3 = half ? acc[7] : acc[3];
    uint2 st;
    st.x = pack2(v0, v1);
    st.y = pack2(v2, v3);
    Mb2[(size_t)wave * 64 + half * 32 + hl] = st;
}

// ---------------- MFMA bf16 GEMM: C[N,BN] = Mb[N,256] @ B[256,BN] ----------------
template <int BN, bool BF16OUT>
__global__ __launch_bounds__(256) void k_gemm(const unsigned short* __restrict__ A,
                                              const unsigned short* __restrict__ Bt,
                                              void* __restrict__ Cout) {
    int wave = threadIdx.x >> 6, lane = threadIdx.x & 63;
    int row0 = blockIdx.x * 64 + wave * 16;
    if (row0 >= NN) return;
    int m = lane & 15, q = lane >> 4;
    const int NT = BN / 16;

    frag_cd acc[NT];
#pragma unroll
    for (int ct = 0; ct < NT; ct++) acc[ct] = (frag_cd){0.f, 0.f, 0.f, 0.f};

    const size_t abase = (size_t)(row0 + m) * 256 + q * 8;
#pragma unroll
    for (int kc = 0; kc < 8; kc++) {
        frag_ab a = *(const frag_ab*)(A + abase + kc * 32);
#pragma unroll
        for (int ct = 0; ct < NT; ct++) {
            frag_ab b = *(const frag_ab*)(Bt + (size_t)(ct * 16 + m) * 256 + kc * 32 + q * 8);
            acc[ct] = __builtin_amdgcn_mfma_f32_16x16x32_bf16(a, b, acc[ct], 0, 0, 0);
        }
    }

#pragma unroll
    for (int ct = 0; ct < NT; ct++) {
#pragma unroll
        for (int i = 0; i < 4; i++) {
            int row = row0 + q * 4 + i;
            int col = ct * 16 + m;
            float v = acc[ct][i];
            if (BF16OUT) {
                v = fmaxf(v, 0.f);
                ((unsigned short*)Cout)[(size_t)row * BN + col] = f2bf(v);
            } else {
                ((float*)Cout)[(size_t)row * BN + col] = v;
            }
        }
    }
}

// ---------------- host ----------------

extern "C" void kernel_launch(void* const* d_in, const int* in_sizes, int n_in,
                              void* d_out, int out_size, void* d_ws, size_t ws_size,
                              hipStream_t stream) {
    const float* x      = (const float*)d_in[0];
    const int*   src    = (const int*)d_in[1];
    const int*   dst    = (const int*)d_in[2];
    const float* basis0 = (const float*)d_in[3];
    const float* coeff0 = (const float*)d_in[4];
    const float* basis1 = (const float*)d_in[5];
    const float* coeff1 = (const float*)d_in[6];
    const float* basis2 = (const float*)d_in[7];
    const float* coeff2 = (const float*)d_in[8];
    float* out = (float*)d_out;

    char* p = (char*)d_ws;
    auto alloc = [&](size_t bytes) {
        char* r = p;
        p += (bytes + 255) & ~(size_t)255;
        return r;
    };
    int*   cnt_srcQ = (int*)alloc((size_t)4 * RN * 4);
    int*   cnt_dstQ = (int*)alloc((size_t)4 * RN * 4);
    float* nsrc     = (float*)alloc((size_t)RN * 4);
    float* ndst     = (float*)alloc((size_t)RN * 4);
    int*   cntd2    = (int*)alloc((size_t)NSEG * 4);
    int*   rp2      = (int*)alloc((size_t)(NSEG + 1) * 4);
    int*   cursor2  = (int*)alloc((size_t)NSEG * 4);
    int*   part     = (int*)alloc((size_t)SCB2 * 4);
    int*   offs     = (int*)alloc((size_t)SCB2 * 4);
    unsigned short* eb = (unsigned short*)alloc((size_t)TE * 2);
    unsigned* Mb   = (unsigned*)alloc((size_t)NN * 128 * 4);        // bf16 [N][256]
    unsigned* Hb   = (unsigned*)alloc((size_t)NN * 64 * 4);         // bf16 [N][128]
    unsigned* Xb   = (unsigned*)alloc((size_t)NN * 64 * 4);         // bf16 [N][128]
    unsigned short* Bt0 = (unsigned short*)alloc((size_t)128 * 256 * 2);
    unsigned short* Bt1 = (unsigned short*)alloc((size_t)128 * 256 * 2);
    unsigned short* Bt2 = (unsigned short*)alloc((size_t)64 * 256 * 2);

    // setup
    k_cvt_x<<<(NN * 32 + 255) / 256, 256, 0, stream>>>((const float4*)x, (uint2*)Xb, NN * 32);
    k_cvt_bt<<<(128 * 256 + 255) / 256, 256, 0, stream>>>(basis0, Bt0, 128);
    k_cvt_bt<<<(128 * 256 + 255) / 256, 256, 0, stream>>>(basis1, Bt1, 128);
    k_cvt_bt<<<(64 * 256 + 255) / 256, 256, 0, stream>>>(basis2, Bt2, 64);
    k_hist<<<256, 1024, 0, stream>>>(src, dst, cnt_srcQ, cnt_dstQ);
    k_sum_norms<<<(RN + 255) / 256, 256, 0, stream>>>(cnt_srcQ, cnt_dstQ, nsrc, ndst, cntd2);
    k_partial<<<SCB2, 256, 0, stream>>>(cntd2, part);
    k_scan_small<<<1, 1024, 0, stream>>>(part, offs);
    k_emit<<<SCB2, 256, 0, stream>>>(cntd2, offs, rp2, cursor2);
    k_fill<<<dim3((EE + 255) / 256, RR), 256, 0, stream>>>(src, dst, cursor2, eb);

    int aggBlocks = NN / 4;
    int gemmBlocks = (NN + 63) / 64;   // 782

    // layer 0: Xb -> Mb -> Hb (relu, bf16)
    k_agg<<<aggBlocks, 256, 0, stream>>>((const uint2*)Xb, rp2, eb, nsrc, ndst, coeff0, (uint2*)Mb);
    k_gemm<128, true><<<gemmBlocks, 256, 0, stream>>>((const unsigned short*)Mb, Bt0, Hb);
    // layer 1
    k_agg<<<aggBlocks, 256, 0, stream>>>((const uint2*)Hb, rp2, eb, nsrc, ndst, coeff1, (uint2*)Mb);
    k_gemm<128, true><<<gemmBlocks, 256, 0, stream>>>((const unsigned short*)Mb, Bt1, Hb);
    // layer 2: final, fp32 out, no relu
    k_agg<<<aggBlocks, 256, 0, stream>>>((const uint2*)Hb, rp2, eb, nsrc, ndst, coeff2, (uint2*)Mb);
    k_gemm<64, false><<<gemmBlocks, 256, 0, stream>>>((const unsigned short*)Mb, Bt2, out);
}

// Round 6
// 491.985 us; speedup vs baseline: 1.1511x; 1.1511x over previous
//
#include <hip/hip_runtime.h>
#include <hip/hip_bf16.h>
#include <cstdint>
#include <cstddef>

#define NN 50000
#define RR 4
#define EE 400000
#define TE (RR*EE)
#define HB 6250          // hist bins per range (8 ranges * 6250 = 50000)
#define RN (RR*NN)       // 200000
#define NSEG (NN*RR)     // 200000 (d-major, r-minor segments)
#define SCB2 782         // ceil(NSEG/256)
#define NBK 256          // dst buckets for the partition
#define BKSZ 196         // nodes per bucket (256*196 >= 50000)
#define CHA 4000         // edges per phase-A block (100 chunks/relation)
#define MAXSPAN 12288    // LDS image capacity (avg span ~6250)

using frag_ab = __attribute__((ext_vector_type(8))) short;   // 8 bf16 (4 VGPRs)
using frag_cd = __attribute__((ext_vector_type(4))) float;   // 4 fp32

static __device__ __forceinline__ unsigned short f2bf(float f) {
    union { float f; unsigned u; } v; v.f = f;
    unsigned r = (v.u + 0x7FFF + ((v.u >> 16) & 1)) >> 16;   // RNE
    return (unsigned short)r;
}
static __device__ __forceinline__ unsigned pack2(float lo, float hi) {
    return (unsigned)f2bf(lo) | ((unsigned)f2bf(hi) << 16);
}

// ---------------- degree histograms: 256 blocks, zero global atomics ----------------
__global__ __launch_bounds__(1024) void k_hist(const int* __restrict__ src,
                                               const int* __restrict__ dst,
                                               int* __restrict__ cnt_srcQ,
                                               int* __restrict__ cnt_dstQ) {
    __shared__ int bins[HB];
    int combo = blockIdx.x >> 5;
    int q     = (blockIdx.x >> 3) & 3;
    int range = blockIdx.x & 7;
    int r = combo >> 1;
    int side = combo & 1;
    const int* arr = (side == 0 ? src : dst) + (size_t)r * EE + (size_t)q * (EE / 4);
    int lo = range * HB;
    for (int i = threadIdx.x; i < HB; i += 1024) bins[i] = 0;
    __syncthreads();
    const int4* a4 = (const int4*)arr;
    for (int i = threadIdx.x; i < EE / 16; i += 1024) {
        int4 v = a4[i];
        int t;
        t = v.x - lo; if ((unsigned)t < (unsigned)HB) atomicAdd(&bins[t], 1);
        t = v.y - lo; if ((unsigned)t < (unsigned)HB) atomicAdd(&bins[t], 1);
        t = v.z - lo; if ((unsigned)t < (unsigned)HB) atomicAdd(&bins[t], 1);
        t = v.w - lo; if ((unsigned)t < (unsigned)HB) atomicAdd(&bins[t], 1);
    }
    __syncthreads();
    int* outp = (side == 0 ? cnt_srcQ : cnt_dstQ) + (size_t)q * RN + (size_t)r * NN + lo;
    for (int i = threadIdx.x; i < HB; i += 1024) outp[i] = bins[i];
}

// sum quarters -> norms ([r*NN+d]) + counts in [d*4+r] layout for the scan
__global__ __launch_bounds__(256) void k_sum_norms(const int* __restrict__ cnt_srcQ,
                                                   const int* __restrict__ cnt_dstQ,
                                                   float* __restrict__ nsrc,
                                                   float* __restrict__ ndst,
                                                   int* __restrict__ cntd2) {
    int i = blockIdx.x * 256 + threadIdx.x;
    if (i >= RN) return;
    int ss = cnt_srcQ[i] + cnt_srcQ[RN + i] + cnt_srcQ[2 * RN + i] + cnt_srcQ[3 * RN + i];
    int ds = cnt_dstQ[i] + cnt_dstQ[RN + i] + cnt_dstQ[2 * RN + i] + cnt_dstQ[3 * RN + i];
    nsrc[i] = 1.0f / sqrtf(fmaxf((float)ss, 1.0f));
    ndst[i] = 1.0f / sqrtf(fmaxf((float)ds, 1.0f));
    int r = i / NN, d = i - r * NN;
    cntd2[d * 4 + r] = ds;
}

// ---------------- 3-phase parallel scan over 200K (d,r) segment counts ----------------
__global__ __launch_bounds__(256) void k_partial(const int* __restrict__ cntd2,
                                                 int* __restrict__ part) {
    __shared__ int s[256];
    int t = threadIdx.x;
    int f = blockIdx.x * 256 + t;
    int v = (f < NSEG) ? cntd2[f] : 0;
    s[t] = v;
    __syncthreads();
    for (int off = 128; off > 0; off >>= 1) {
        if (t < off) s[t] += s[t + off];
        __syncthreads();
    }
    if (t == 0) part[blockIdx.x] = s[0];
}

__global__ __launch_bounds__(1024) void k_scan_small(const int* __restrict__ part,
                                                     int* __restrict__ offs) {
    __shared__ int s[1024];
    int t = threadIdx.x;
    s[t] = (t < SCB2) ? part[t] : 0;
    __syncthreads();
    for (int off = 1; off < 1024; off <<= 1) {
        int v = (t >= off) ? s[t - off] : 0;
        __syncthreads();
        s[t] += v;
        __syncthreads();
    }
    if (t < SCB2) offs[t] = (t == 0) ? 0 : s[t - 1];
}

__global__ __launch_bounds__(256) void k_emit(const int* __restrict__ cntd2,
                                              const int* __restrict__ offs,
                                              int* __restrict__ rp2) {
    __shared__ int s[256];
    int t = threadIdx.x;
    int f = blockIdx.x * 256 + t;
    int v = (f < NSEG) ? cntd2[f] : 0;
    s[t] = v;
    __syncthreads();
    for (int off = 1; off < 256; off <<= 1) {
        int u = (t >= off) ? s[t - off] : 0;
        __syncthreads();
        s[t] += u;
        __syncthreads();
    }
    if (f < NSEG) rp2[f] = offs[blockIdx.x] + s[t] - v;
    if (f == NSEG - 1) rp2[NSEG] = TE;
}

// ---------------- two-phase edge partition (replaces scattered k_fill) ----------------
// gcur[b] = staging cursor for bucket b, init to bucket's base offset in edge space
__global__ __launch_bounds__(256) void k_initg(const int* __restrict__ rp2,
                                               int* __restrict__ gcur) {
    int t = threadIdx.x;
    gcur[t] = rp2[t * BKSZ * 4];
}

// Phase A: multi-split edges into 256 dst-range buckets.
// payload: src(16) | r(2 @16) | dlocal(8 @18)
__global__ __launch_bounds__(256) void k_fillA(const int* __restrict__ src,
                                               const int* __restrict__ dst,
                                               int* __restrict__ gcur,
                                               unsigned* __restrict__ stage) {
    __shared__ int cnt[NBK];
    __shared__ int rcur[NBK];
    int r = blockIdx.y;
    int base_e = blockIdx.x * CHA;
    int t = threadIdx.x;
    cnt[t] = 0;
    __syncthreads();
    const int* dr = dst + (size_t)r * EE;
    const int* sr = src + (size_t)r * EE;
    for (int i = base_e + t; i < base_e + CHA; i += 256) {
        int d = dr[i];
        atomicAdd(&cnt[d / BKSZ], 1);
    }
    __syncthreads();
    rcur[t] = atomicAdd(&gcur[t], cnt[t]);
    __syncthreads();
    for (int i = base_e + t; i < base_e + CHA; i += 256) {
        int d = dr[i];
        int s = sr[i];
        int b = d / BKSZ;
        int dl = d - b * BKSZ;
        int pos = atomicAdd(&rcur[b], 1);
        stage[pos] = (unsigned)s | ((unsigned)r << 16) | ((unsigned)dl << 18);
    }
}

// Phase B: one block per bucket; order edges into exact (d,r) segments via an
// LDS image of the bucket's contiguous eb span, then flush dense.
__global__ __launch_bounds__(256) void k_fillB(const unsigned* __restrict__ stage,
                                               const int* __restrict__ rp2,
                                               unsigned short* __restrict__ eb) {
    __shared__ unsigned short img[MAXSPAN];
    __shared__ int lcur[BKSZ * 4];
    int b = blockIdx.x;
    int t = threadIdx.x;
    int node0 = b * BKSZ;
    int nodes = min(BKSZ, NN - node0);
    int nseg_local = nodes * 4;
    int segbase = node0 * 4;
    for (int i = t; i < nseg_local; i += 256) lcur[i] = rp2[segbase + i];
    __syncthreads();
    int S0 = lcur[0];
    int S1 = rp2[segbase + nseg_local];   // rp2[NSEG]=TE for last bucket
    int span = S1 - S0;
    if (span <= MAXSPAN) {
        for (int i = S0 + t; i < S1; i += 256) {
            unsigned w = stage[i];
            int seg = (int)((w >> 18) & 0xFF) * 4 + (int)((w >> 16) & 3);
            int pos = atomicAdd(&lcur[seg], 1);
            img[pos - S0] = (unsigned short)(w & 0xFFFF);
        }
        __syncthreads();
        for (int i = t; i < span; i += 256) eb[S0 + i] = img[i];
    } else {  // overflow fallback (statistically unreachable)
        for (int i = S0 + t; i < S1; i += 256) {
            unsigned w = stage[i];
            int seg = (int)((w >> 18) & 0xFF) * 4 + (int)((w >> 16) & 3);
            int pos = atomicAdd(&lcur[seg], 1);
            eb[pos] = (unsigned short)(w & 0xFFFF);
        }
    }
}

// ---------------- converts ----------------
__global__ __launch_bounds__(256) void k_cvt_x(const float4* __restrict__ x4,
                                               uint2* __restrict__ o, int n4) {
    int i = blockIdx.x * 256 + threadIdx.x;
    if (i >= n4) return;
    float4 v = x4[i];
    o[i] = make_uint2(pack2(v.x, v.y), pack2(v.z, v.w));
}

// Bt[n][k] = bf16(basis[k][n]); basis flat [256][BN]
__global__ __launch_bounds__(256) void k_cvt_bt(const float* __restrict__ B,
                                                unsigned short* __restrict__ Bt, int BN) {
    int o = blockIdx.x * 256 + threadIdx.x;
    if (o >= BN * 256) return;
    int k = o & 255, n = o >> 8;
    Bt[o] = f2bf(B[k * BN + n]);
}

// ---------------- aggregation: one wave per dst node, half-wave per edge ----------------
__global__ __launch_bounds__(256) void k_agg(const uint2* __restrict__ hb2,
                                             const int* __restrict__ rp2,
                                             const unsigned short* __restrict__ eb,
                                             const float* __restrict__ nsrc,
                                             const float* __restrict__ ndst,
                                             const float* __restrict__ coeff,
                                             uint2* __restrict__ Mb2) {
    int wave = (blockIdx.x * 256 + threadIdx.x) >> 6;
    int lane = threadIdx.x & 63;
    if (wave >= NN) return;
    int half = lane >> 5, hl = lane & 31;

    float acc[8];
#pragma unroll
    for (int i = 0; i < 8; i++) acc[i] = 0.f;

    int4 seg = *(const int4*)&rp2[wave * 4];
    int bounds[5] = {seg.x, seg.y, seg.z, seg.w, rp2[wave * 4 + 4]};

#pragma unroll
    for (int r = 0; r < RR; r++) {
        int e0 = bounds[r], e1 = bounds[r + 1];
        if (e0 >= e1) continue;
        float nd = ndst[r * NN + wave];
        float cA = coeff[r * 2 + 0] * nd;
        float cB = coeff[r * 2 + 1] * nd;

        int e = e0;
        for (; e + 3 < e1; e += 4) {
            int sA = eb[e + half];
            int sB = eb[e + 2 + half];
            float nsA = nsrc[r * NN + sA];
            float nsB = nsrc[r * NN + sB];
            uint2 hvA = hb2[(size_t)sA * 32 + hl];
            uint2 hvB = hb2[(size_t)sB * 32 + hl];
            float wA0 = cA * nsA, wA1 = cB * nsA;
            float wB0 = cA * nsB, wB1 = cB * nsB;
            float a0 = __uint_as_float(hvA.x << 16);
            float a1 = __uint_as_float(hvA.x & 0xFFFF0000u);
            float a2 = __uint_as_float(hvA.y << 16);
            float a3 = __uint_as_float(hvA.y & 0xFFFF0000u);
            acc[0] += wA0 * a0; acc[1] += wA0 * a1; acc[2] += wA0 * a2; acc[3] += wA0 * a3;
            acc[4] += wA1 * a0; acc[5] += wA1 * a1; acc[6] += wA1 * a2; acc[7] += wA1 * a3;
            float b0 = __uint_as_float(hvB.x << 16);
            float b1 = __uint_as_float(hvB.x & 0xFFFF0000u);
            float b2 = __uint_as_float(hvB.y << 16);
            float b3 = __uint_as_float(hvB.y & 0xFFFF0000u);
            acc[0] += wB0 * b0; acc[1] += wB0 * b1; acc[2] += wB0 * b2; acc[3] += wB0 * b3;
            acc[4] += wB1 * b0; acc[5] += wB1 * b1; acc[6] += wB1 * b2; acc[7] += wB1 * b3;
        }
        for (; e < e1; e += 2) {
            int ee = e + half;
            if (ee < e1) {
                int s = eb[ee];
                float ns = nsrc[r * NN + s];
                uint2 hv = hb2[(size_t)s * 32 + hl];
                float w0 = cA * ns, w1 = cB * ns;
                float a0 = __uint_as_float(hv.x << 16);
                float a1 = __uint_as_float(hv.x & 0xFFFF0000u);
                float a2 = __uint_as_float(hv.y << 16);
                float a3 = __uint_as_float(hv.y & 0xFFFF0000u);
                acc[0] += w0 * a0; acc[1] += w0 * a1; acc[2] += w0 * a2; acc[3] += w0 * a3;
                acc[4] += w1 * a0; acc[5] += w1 * a1; acc[6] += w1 * a2; acc[7] += w1 * a3;
            }
        }
    }

#pragma unroll
    for (int i = 0; i < 8; i++) acc[i] += __shfl_xor(acc[i], 32, 64);

    float v0 = half ? acc[4] : acc[0];
    float v1 = half ? acc[5] : acc[1];
    float v2 = half ? acc[6] : acc[2];
    float v3 = half ? acc[7] : acc[3];
    uint2 st;
    st.x = pack2(v0, v1);
    st.y = pack2(v2, v3);
    Mb2[(size_t)wave * 64 + half * 32 + hl] = st;
}

// ---------------- MFMA bf16 GEMM: C[N,BN] = Mb[N,256] @ B[256,BN] ----------------
template <int BN, bool BF16OUT>
__global__ __launch_bounds__(256) void k_gemm(const unsigned short* __restrict__ A,
                                              const unsigned short* __restrict__ Bt,
                                              void* __restrict__ Cout) {
    int wave = threadIdx.x >> 6, lane = threadIdx.x & 63;
    int row0 = blockIdx.x * 64 + wave * 16;
    if (row0 >= NN) return;
    int m = lane & 15, q = lane >> 4;
    const int NT = BN / 16;

    frag_cd acc[NT];
#pragma unroll
    for (int ct = 0; ct < NT; ct++) acc[ct] = (frag_cd){0.f, 0.f, 0.f, 0.f};

    const size_t abase = (size_t)(row0 + m) * 256 + q * 8;
#pragma unroll
    for (int kc = 0; kc < 8; kc++) {
        frag_ab a = *(const frag_ab*)(A + abase + kc * 32);
#pragma unroll
        for (int ct = 0; ct < NT; ct++) {
            frag_ab b = *(const frag_ab*)(Bt + (size_t)(ct * 16 + m) * 256 + kc * 32 + q * 8);
            acc[ct] = __builtin_amdgcn_mfma_f32_16x16x32_bf16(a, b, acc[ct], 0, 0, 0);
        }
    }

#pragma unroll
    for (int ct = 0; ct < NT; ct++) {
#pragma unroll
        for (int i = 0; i < 4; i++) {
            int row = row0 + q * 4 + i;
            int col = ct * 16 + m;
            float v = acc[ct][i];
            if (BF16OUT) {
                v = fmaxf(v, 0.f);
                ((unsigned short*)Cout)[(size_t)row * BN + col] = f2bf(v);
            } else {
                ((float*)Cout)[(size_t)row * BN + col] = v;
            }
        }
    }
}

// ---------------- host ----------------

extern "C" void kernel_launch(void* const* d_in, const int* in_sizes, int n_in,
                              void* d_out, int out_size, void* d_ws, size_t ws_size,
                              hipStream_t stream) {
    const float* x      = (const float*)d_in[0];
    const int*   src    = (const int*)d_in[1];
    const int*   dst    = (const int*)d_in[2];
    const float* basis0 = (const float*)d_in[3];
    const float* coeff0 = (const float*)d_in[4];
    const float* basis1 = (const float*)d_in[5];
    const float* coeff1 = (const float*)d_in[6];
    const float* basis2 = (const float*)d_in[7];
    const float* coeff2 = (const float*)d_in[8];
    float* out = (float*)d_out;

    char* p = (char*)d_ws;
    auto alloc = [&](size_t bytes) {
        char* r = p;
        p += (bytes + 255) & ~(size_t)255;
        return r;
    };
    int*   cnt_srcQ = (int*)alloc((size_t)4 * RN * 4);
    int*   cnt_dstQ = (int*)alloc((size_t)4 * RN * 4);
    float* nsrc     = (float*)alloc((size_t)RN * 4);
    float* ndst     = (float*)alloc((size_t)RN * 4);
    int*   cntd2    = (int*)alloc((size_t)NSEG * 4);
    int*   rp2      = (int*)alloc((size_t)(NSEG + 1) * 4);
    int*   part     = (int*)alloc((size_t)SCB2 * 4);
    int*   offs     = (int*)alloc((size_t)SCB2 * 4);
    int*   gcur     = (int*)alloc((size_t)NBK * 4);
    unsigned* stage = (unsigned*)alloc((size_t)TE * 4);
    unsigned short* eb = (unsigned short*)alloc((size_t)TE * 2);
    unsigned* Mb   = (unsigned*)alloc((size_t)NN * 128 * 4);        // bf16 [N][256]
    unsigned* Hb   = (unsigned*)alloc((size_t)NN * 64 * 4);         // bf16 [N][128]
    unsigned* Xb   = (unsigned*)alloc((size_t)NN * 64 * 4);         // bf16 [N][128]
    unsigned short* Bt0 = (unsigned short*)alloc((size_t)128 * 256 * 2);
    unsigned short* Bt1 = (unsigned short*)alloc((size_t)128 * 256 * 2);
    unsigned short* Bt2 = (unsigned short*)alloc((size_t)64 * 256 * 2);

    // setup
    k_cvt_x<<<(NN * 32 + 255) / 256, 256, 0, stream>>>((const float4*)x, (uint2*)Xb, NN * 32);
    k_cvt_bt<<<(128 * 256 + 255) / 256, 256, 0, stream>>>(basis0, Bt0, 128);
    k_cvt_bt<<<(128 * 256 + 255) / 256, 256, 0, stream>>>(basis1, Bt1, 128);
    k_cvt_bt<<<(64 * 256 + 255) / 256, 256, 0, stream>>>(basis2, Bt2, 64);
    k_hist<<<256, 1024, 0, stream>>>(src, dst, cnt_srcQ, cnt_dstQ);
    k_sum_norms<<<(RN + 255) / 256, 256, 0, stream>>>(cnt_srcQ, cnt_dstQ, nsrc, ndst, cntd2);
    k_partial<<<SCB2, 256, 0, stream>>>(cntd2, part);
    k_scan_small<<<1, 1024, 0, stream>>>(part, offs);
    k_emit<<<SCB2, 256, 0, stream>>>(cntd2, offs, rp2);
    k_initg<<<1, NBK, 0, stream>>>(rp2, gcur);
    k_fillA<<<dim3(EE / CHA, RR), 256, 0, stream>>>(src, dst, gcur, stage);
    k_fillB<<<NBK, 256, 0, stream>>>(stage, rp2, eb);

    int aggBlocks = NN / 4;
    int gemmBlocks = (NN + 63) / 64;   // 782

    // layer 0: Xb -> Mb -> Hb (relu, bf16)
    k_agg<<<aggBlocks, 256, 0, stream>>>((const uint2*)Xb, rp2, eb, nsrc, ndst, coeff0, (uint2*)Mb);
    k_gemm<128, true><<<gemmBlocks, 256, 0, stream>>>((const unsigned short*)Mb, Bt0, Hb);
    // layer 1
    k_agg<<<aggBlocks, 256, 0, stream>>>((const uint2*)Hb, rp2, eb, nsrc, ndst, coeff1, (uint2*)Mb);
    k_gemm<128, true><<<gemmBlocks, 256, 0, stream>>>((const unsigned short*)Mb, Bt1, Hb);
    // layer 2: final, fp32 out, no relu
    k_agg<<<aggBlocks, 256, 0, stream>>>((const uint2*)Hb, rp2, eb, nsrc, ndst, coeff2, (uint2*)Mb);
    k_gemm<64, false><<<gemmBlocks, 256, 0, stream>>>((const unsigned short*)Mb, Bt2, out);
}

// Round 7
// 468.041 us; speedup vs baseline: 1.2100x; 1.0512x over previous
//
#include <hip/hip_runtime.h>
#include <hip/hip_bf16.h>
#include <cstdint>
#include <cstddef>

#define NN 50000
#define RR 4
#define EE 400000
#define TE (RR*EE)
#define HR 12500         // hist bins per range (4 ranges * 12500 = 50000)
#define RN (RR*NN)       // 200000
#define NSEG (NN*RR)     // 200000 (d-major, r-minor segments)
#define SCB2 782         // ceil(NSEG/256)
#define NBK 256          // dst buckets for the partition
#define BKSZ 196         // nodes per bucket (256*196 >= 50000)
#define CHA 4000         // edges per phase-A block (100 chunks/relation)
#define MAXSPAN 12288    // LDS image capacity (avg span ~6250)

using frag_ab = __attribute__((ext_vector_type(8))) short;   // 8 bf16 (4 VGPRs)
using frag_cd = __attribute__((ext_vector_type(4))) float;   // 4 fp32

static __device__ __forceinline__ unsigned short f2bf(float f) {
    union { float f; unsigned u; } v; v.f = f;
    unsigned r = (v.u + 0x7FFF + ((v.u >> 16) & 1)) >> 16;   // RNE
    return (unsigned short)r;
}
static __device__ __forceinline__ unsigned pack2(float lo, float hi) {
    return (unsigned)f2bf(lo) | ((unsigned)f2bf(hi) << 16);
}

// ---------------- degree histograms: packed 16-bit LDS counters ----------------
// 128 blocks: combo = bid>>4 (r*2+side), range = (bid>>2)&3, chunk = bid&3.
// 4 ranges (vs 8) halves the read amplification; two 16-bit counters per uint.
__global__ __launch_bounds__(1024) void k_hist(const int* __restrict__ src,
                                               const int* __restrict__ dst,
                                               int* __restrict__ cnt_srcQ,
                                               int* __restrict__ cnt_dstQ) {
    __shared__ unsigned bins[HR / 2];   // 6250 uints = 25 KB
    int combo = blockIdx.x >> 4;
    int range = (blockIdx.x >> 2) & 3;
    int qc    = blockIdx.x & 3;
    int r = combo >> 1;
    int side = combo & 1;
    const int* arr = (side == 0 ? src : dst) + (size_t)r * EE + (size_t)qc * (EE / 4);
    int lo = range * HR;
    for (int i = threadIdx.x; i < HR / 2; i += 1024) bins[i] = 0;
    __syncthreads();
    const int4* a4 = (const int4*)arr;
    for (int i = threadIdx.x; i < EE / 16; i += 1024) {
        int4 v = a4[i];
        int t;
        t = v.x - lo; if ((unsigned)t < (unsigned)HR) atomicAdd(&bins[t >> 1], 1u << ((t & 1) * 16));
        t = v.y - lo; if ((unsigned)t < (unsigned)HR) atomicAdd(&bins[t >> 1], 1u << ((t & 1) * 16));
        t = v.z - lo; if ((unsigned)t < (unsigned)HR) atomicAdd(&bins[t >> 1], 1u << ((t & 1) * 16));
        t = v.w - lo; if ((unsigned)t < (unsigned)HR) atomicAdd(&bins[t >> 1], 1u << ((t & 1) * 16));
    }
    __syncthreads();
    int* outp = (side == 0 ? cnt_srcQ : cnt_dstQ) + (size_t)qc * RN + (size_t)r * NN + lo;
    for (int i = threadIdx.x; i < HR / 2; i += 1024) {
        unsigned b = bins[i];
        outp[2 * i]     = (int)(b & 0xFFFFu);
        outp[2 * i + 1] = (int)(b >> 16);
    }
}

// sum quarters -> norms ([r*NN+d]) + counts in [d*4+r] layout for the scan
__global__ __launch_bounds__(256) void k_sum_norms(const int* __restrict__ cnt_srcQ,
                                                   const int* __restrict__ cnt_dstQ,
                                                   float* __restrict__ nsrc,
                                                   float* __restrict__ ndst,
                                                   int* __restrict__ cntd2) {
    int i = blockIdx.x * 256 + threadIdx.x;
    if (i >= RN) return;
    int ss = cnt_srcQ[i] + cnt_srcQ[RN + i] + cnt_srcQ[2 * RN + i] + cnt_srcQ[3 * RN + i];
    int ds = cnt_dstQ[i] + cnt_dstQ[RN + i] + cnt_dstQ[2 * RN + i] + cnt_dstQ[3 * RN + i];
    nsrc[i] = 1.0f / sqrtf(fmaxf((float)ss, 1.0f));
    ndst[i] = 1.0f / sqrtf(fmaxf((float)ds, 1.0f));
    int r = i / NN, d = i - r * NN;
    cntd2[d * 4 + r] = ds;
}

// ---------------- 3-phase parallel scan over 200K (d,r) segment counts ----------------
__global__ __launch_bounds__(256) void k_partial(const int* __restrict__ cntd2,
                                                 int* __restrict__ part) {
    __shared__ int s[256];
    int t = threadIdx.x;
    int f = blockIdx.x * 256 + t;
    int v = (f < NSEG) ? cntd2[f] : 0;
    s[t] = v;
    __syncthreads();
    for (int off = 128; off > 0; off >>= 1) {
        if (t < off) s[t] += s[t + off];
        __syncthreads();
    }
    if (t == 0) part[blockIdx.x] = s[0];
}

__global__ __launch_bounds__(1024) void k_scan_small(const int* __restrict__ part,
                                                     int* __restrict__ offs) {
    __shared__ int s[1024];
    int t = threadIdx.x;
    s[t] = (t < SCB2) ? part[t] : 0;
    __syncthreads();
    for (int off = 1; off < 1024; off <<= 1) {
        int v = (t >= off) ? s[t - off] : 0;
        __syncthreads();
        s[t] += v;
        __syncthreads();
    }
    if (t < SCB2) offs[t] = (t == 0) ? 0 : s[t - 1];
}

__global__ __launch_bounds__(256) void k_emit(const int* __restrict__ cntd2,
                                              const int* __restrict__ offs,
                                              int* __restrict__ rp2) {
    __shared__ int s[256];
    int t = threadIdx.x;
    int f = blockIdx.x * 256 + t;
    int v = (f < NSEG) ? cntd2[f] : 0;
    s[t] = v;
    __syncthreads();
    for (int off = 1; off < 256; off <<= 1) {
        int u = (t >= off) ? s[t - off] : 0;
        __syncthreads();
        s[t] += u;
        __syncthreads();
    }
    if (f < NSEG) rp2[f] = offs[blockIdx.x] + s[t] - v;
    if (f == NSEG - 1) rp2[NSEG] = TE;
}

// ---------------- two-phase edge partition ----------------
__global__ __launch_bounds__(256) void k_initg(const int* __restrict__ rp2,
                                               int* __restrict__ gcur) {
    int t = threadIdx.x;
    gcur[t] = rp2[t * BKSZ * 4];
}

// Phase A: multi-split edges into 256 dst-range buckets.
// payload: src(16) | r(2 @16) | dlocal(8 @18)
__global__ __launch_bounds__(256) void k_fillA(const int* __restrict__ src,
                                               const int* __restrict__ dst,
                                               int* __restrict__ gcur,
                                               unsigned* __restrict__ stage) {
    __shared__ int cnt[NBK];
    __shared__ int rcur[NBK];
    int r = blockIdx.y;
    int base_e = blockIdx.x * CHA;
    int t = threadIdx.x;
    cnt[t] = 0;
    __syncthreads();
    const int* dr = dst + (size_t)r * EE;
    const int* sr = src + (size_t)r * EE;
    for (int i = base_e + t; i < base_e + CHA; i += 256) {
        int d = dr[i];
        atomicAdd(&cnt[d / BKSZ], 1);
    }
    __syncthreads();
    rcur[t] = atomicAdd(&gcur[t], cnt[t]);
    __syncthreads();
    for (int i = base_e + t; i < base_e + CHA; i += 256) {
        int d = dr[i];
        int s = sr[i];
        int b = d / BKSZ;
        int dl = d - b * BKSZ;
        int pos = atomicAdd(&rcur[b], 1);
        stage[pos] = (unsigned)s | ((unsigned)r << 16) | ((unsigned)dl << 18);
    }
}

// Phase B: one block per bucket; order into exact (d,r) segments via LDS image.
__global__ __launch_bounds__(256) void k_fillB(const unsigned* __restrict__ stage,
                                               const int* __restrict__ rp2,
                                               unsigned short* __restrict__ eb) {
    __shared__ unsigned short img[MAXSPAN];
    __shared__ int lcur[BKSZ * 4];
    int b = blockIdx.x;
    int t = threadIdx.x;
    int node0 = b * BKSZ;
    int nodes = min(BKSZ, NN - node0);
    int nseg_local = nodes * 4;
    int segbase = node0 * 4;
    for (int i = t; i < nseg_local; i += 256) lcur[i] = rp2[segbase + i];
    __syncthreads();
    int S0 = lcur[0];
    int S1 = rp2[segbase + nseg_local];
    int span = S1 - S0;
    if (span <= MAXSPAN) {
        for (int i = S0 + t; i < S1; i += 256) {
            unsigned w = stage[i];
            int seg = (int)((w >> 18) & 0xFF) * 4 + (int)((w >> 16) & 3);
            int pos = atomicAdd(&lcur[seg], 1);
            img[pos - S0] = (unsigned short)(w & 0xFFFF);
        }
        __syncthreads();
        for (int i = t; i < span; i += 256) eb[S0 + i] = img[i];
    } else {
        for (int i = S0 + t; i < S1; i += 256) {
            unsigned w = stage[i];
            int seg = (int)((w >> 18) & 0xFF) * 4 + (int)((w >> 16) & 3);
            int pos = atomicAdd(&lcur[seg], 1);
            eb[pos] = (unsigned short)(w & 0xFFFF);
        }
    }
}

// ---------------- converts ----------------
__global__ __launch_bounds__(256) void k_cvt_x(const float4* __restrict__ x4,
                                               uint2* __restrict__ o, int n4) {
    int i = blockIdx.x * 256 + threadIdx.x;
    if (i >= n4) return;
    float4 v = x4[i];
    o[i] = make_uint2(pack2(v.x, v.y), pack2(v.z, v.w));
}

// Bt[n][k] = bf16(basis[k][n]); basis flat [256][BN]
__global__ __launch_bounds__(256) void k_cvt_bt(const float* __restrict__ B,
                                                unsigned short* __restrict__ Bt, int BN) {
    int o = blockIdx.x * 256 + threadIdx.x;
    if (o >= BN * 256) return;
    int k = o & 255, n = o >> 8;
    Bt[o] = f2bf(B[k * BN + n]);
}

// ---------------- aggregation: one wave per dst node, quarter-wave per edge ----------------
// hb4: bf16 rows of 128 ch = 16 uint4 (256 B). Lane (q,hl): quarter q, hl in [0,16).
// Each quarter-wave gathers one full row per edge via uint4 (16 B/lane).
__global__ __launch_bounds__(256) void k_agg(const uint4* __restrict__ hb4,
                                             const int* __restrict__ rp2,
                                             const unsigned short* __restrict__ eb,
                                             const float* __restrict__ nsrc,
                                             const float* __restrict__ ndst,
                                             const float* __restrict__ coeff,
                                             uint2* __restrict__ Mb2) {
    int wave = (blockIdx.x * 256 + threadIdx.x) >> 6;
    int lane = threadIdx.x & 63;
    if (wave >= NN) return;
    int q = lane >> 4, hl = lane & 15;

    float a0[8], a1[8];
#pragma unroll
    for (int i = 0; i < 8; i++) { a0[i] = 0.f; a1[i] = 0.f; }

    int4 seg = *(const int4*)&rp2[wave * 4];
    int bounds[5] = {seg.x, seg.y, seg.z, seg.w, rp2[wave * 4 + 4]};

#pragma unroll
    for (int r = 0; r < RR; r++) {
        int e0 = bounds[r], e1 = bounds[r + 1];
        if (e0 >= e1) continue;
        float nd = ndst[r * NN + wave];
        float cA = coeff[r * 2 + 0] * nd;
        float cB = coeff[r * 2 + 1] * nd;
        const float* nsr = nsrc + r * NN;

        int e = e0;
        // 8 edges/iter: 2 per quarter, 2 gathers in flight per quarter
        for (; e + 7 < e1; e += 8) {
            int sA = eb[e + q];
            int sB = eb[e + 4 + q];
            float nsA = nsr[sA];
            float nsB = nsr[sB];
            uint4 hA = hb4[(size_t)sA * 16 + hl];
            uint4 hB = hb4[(size_t)sB * 16 + hl];
            float wA0 = cA * nsA, wA1 = cB * nsA;
            float wB0 = cA * nsB, wB1 = cB * nsB;
            unsigned ua[4] = {hA.x, hA.y, hA.z, hA.w};
#pragma unroll
            for (int j = 0; j < 4; j++) {
                float lo = __uint_as_float(ua[j] << 16);
                float hi = __uint_as_float(ua[j] & 0xFFFF0000u);
                a0[2 * j]     += wA0 * lo; a0[2 * j + 1] += wA0 * hi;
                a1[2 * j]     += wA1 * lo; a1[2 * j + 1] += wA1 * hi;
            }
            unsigned ub[4] = {hB.x, hB.y, hB.z, hB.w};
#pragma unroll
            for (int j = 0; j < 4; j++) {
                float lo = __uint_as_float(ub[j] << 16);
                float hi = __uint_as_float(ub[j] & 0xFFFF0000u);
                a0[2 * j]     += wB0 * lo; a0[2 * j + 1] += wB0 * hi;
                a1[2 * j]     += wB1 * lo; a1[2 * j + 1] += wB1 * hi;
            }
        }
        // masked tail: 4 edges/iter, inactive quarters contribute weight 0
        for (; e < e1; e += 4) {
            int ee = e + q;
            bool act = ee < e1;
            int s = eb[act ? ee : e];
            float ns = act ? nsr[s] : 0.f;
            uint4 h = hb4[(size_t)s * 16 + hl];
            float w0 = cA * ns, w1 = cB * ns;
            unsigned u[4] = {h.x, h.y, h.z, h.w};
#pragma unroll
            for (int j = 0; j < 4; j++) {
                float lo = __uint_as_float(u[j] << 16);
                float hi = __uint_as_float(u[j] & 0xFFFF0000u);
                a0[2 * j]     += w0 * lo; a0[2 * j + 1] += w0 * hi;
                a1[2 * j]     += w1 * lo; a1[2 * j + 1] += w1 * hi;
            }
        }
    }

    // cross-quarter reduce (xor 16, then 32): all quarters end with full sums
#pragma unroll
    for (int i = 0; i < 8; i++) {
        a0[i] += __shfl_xor(a0[i], 16, 64);
        a0[i] += __shfl_xor(a0[i], 32, 64);
        a1[i] += __shfl_xor(a1[i], 16, 64);
        a1[i] += __shfl_xor(a1[i], 32, 64);
    }

    // lane (q,hl) stores 4 ch: coeff c = q>>1, chan base = hl*8 + (q&1)*4
    int c = q >> 1, h4 = q & 1;
    float b0 = c ? (h4 ? a1[4] : a1[0]) : (h4 ? a0[4] : a0[0]);
    float b1 = c ? (h4 ? a1[5] : a1[1]) : (h4 ? a0[5] : a0[1]);
    float b2 = c ? (h4 ? a1[6] : a1[2]) : (h4 ? a0[6] : a0[2]);
    float b3 = c ? (h4 ? a1[7] : a1[3]) : (h4 ? a0[7] : a0[3]);
    uint2 st;
    st.x = pack2(b0, b1);
    st.y = pack2(b2, b3);
    Mb2[(size_t)wave * 64 + c * 32 + hl * 2 + h4] = st;
}

// ---------------- MFMA bf16 GEMM: C[N,BN] = Mb[N,256] @ B[256,BN] ----------------
template <int BN, bool BF16OUT>
__global__ __launch_bounds__(256) void k_gemm(const unsigned short* __restrict__ A,
                                              const unsigned short* __restrict__ Bt,
                                              void* __restrict__ Cout) {
    int wave = threadIdx.x >> 6, lane = threadIdx.x & 63;
    int row0 = blockIdx.x * 64 + wave * 16;
    if (row0 >= NN) return;
    int m = lane & 15, q = lane >> 4;
    const int NT = BN / 16;

    frag_cd acc[NT];
#pragma unroll
    for (int ct = 0; ct < NT; ct++) acc[ct] = (frag_cd){0.f, 0.f, 0.f, 0.f};

    const size_t abase = (size_t)(row0 + m) * 256 + q * 8;
#pragma unroll
    for (int kc = 0; kc < 8; kc++) {
        frag_ab a = *(const frag_ab*)(A + abase + kc * 32);
#pragma unroll
        for (int ct = 0; ct < NT; ct++) {
            frag_ab b = *(const frag_ab*)(Bt + (size_t)(ct * 16 + m) * 256 + kc * 32 + q * 8);
            acc[ct] = __builtin_amdgcn_mfma_f32_16x16x32_bf16(a, b, acc[ct], 0, 0, 0);
        }
    }

#pragma unroll
    for (int ct = 0; ct < NT; ct++) {
#pragma unroll
        for (int i = 0; i < 4; i++) {
            int row = row0 + q * 4 + i;
            int col = ct * 16 + m;
            float v = acc[ct][i];
            if (BF16OUT) {
                v = fmaxf(v, 0.f);
                ((unsigned short*)Cout)[(size_t)row * BN + col] = f2bf(v);
            } else {
                ((float*)Cout)[(size_t)row * BN + col] = v;
            }
        }
    }
}

// ---------------- host ----------------

extern "C" void kernel_launch(void* const* d_in, const int* in_sizes, int n_in,
                              void* d_out, int out_size, void* d_ws, size_t ws_size,
                              hipStream_t stream) {
    const float* x      = (const float*)d_in[0];
    const int*   src    = (const int*)d_in[1];
    const int*   dst    = (const int*)d_in[2];
    const float* basis0 = (const float*)d_in[3];
    const float* coeff0 = (const float*)d_in[4];
    const float* basis1 = (const float*)d_in[5];
    const float* coeff1 = (const float*)d_in[6];
    const float* basis2 = (const float*)d_in[7];
    const float* coeff2 = (const float*)d_in[8];
    float* out = (float*)d_out;

    char* p = (char*)d_ws;
    auto alloc = [&](size_t bytes) {
        char* r = p;
        p += (bytes + 255) & ~(size_t)255;
        return r;
    };
    int*   cnt_srcQ = (int*)alloc((size_t)4 * RN * 4);
    int*   cnt_dstQ = (int*)alloc((size_t)4 * RN * 4);
    float* nsrc     = (float*)alloc((size_t)RN * 4);
    float* ndst     = (float*)alloc((size_t)RN * 4);
    int*   cntd2    = (int*)alloc((size_t)NSEG * 4);
    int*   rp2      = (int*)alloc((size_t)(NSEG + 1) * 4);
    int*   part     = (int*)alloc((size_t)SCB2 * 4);
    int*   offs     = (int*)alloc((size_t)SCB2 * 4);
    int*   gcur     = (int*)alloc((size_t)NBK * 4);
    unsigned* stage = (unsigned*)alloc((size_t)TE * 4);
    unsigned short* eb = (unsigned short*)alloc((size_t)TE * 2);
    unsigned* Mb   = (unsigned*)alloc((size_t)NN * 128 * 4);        // bf16 [N][256]
    unsigned* Hb   = (unsigned*)alloc((size_t)NN * 64 * 4);         // bf16 [N][128]
    unsigned* Xb   = (unsigned*)alloc((size_t)NN * 64 * 4);         // bf16 [N][128]
    unsigned short* Bt0 = (unsigned short*)alloc((size_t)128 * 256 * 2);
    unsigned short* Bt1 = (unsigned short*)alloc((size_t)128 * 256 * 2);
    unsigned short* Bt2 = (unsigned short*)alloc((size_t)64 * 256 * 2);

    // setup
    k_cvt_x<<<(NN * 32 + 255) / 256, 256, 0, stream>>>((const float4*)x, (uint2*)Xb, NN * 32);
    k_cvt_bt<<<(128 * 256 + 255) / 256, 256, 0, stream>>>(basis0, Bt0, 128);
    k_cvt_bt<<<(128 * 256 + 255) / 256, 256, 0, stream>>>(basis1, Bt1, 128);
    k_cvt_bt<<<(64 * 256 + 255) / 256, 256, 0, stream>>>(basis2, Bt2, 64);
    k_hist<<<128, 1024, 0, stream>>>(src, dst, cnt_srcQ, cnt_dstQ);
    k_sum_norms<<<(RN + 255) / 256, 256, 0, stream>>>(cnt_srcQ, cnt_dstQ, nsrc, ndst, cntd2);
    k_partial<<<SCB2, 256, 0, stream>>>(cntd2, part);
    k_scan_small<<<1, 1024, 0, stream>>>(part, offs);
    k_emit<<<SCB2, 256, 0, stream>>>(cntd2, offs, rp2);
    k_initg<<<1, NBK, 0, stream>>>(rp2, gcur);
    k_fillA<<<dim3(EE / CHA, RR), 256, 0, stream>>>(src, dst, gcur, stage);
    k_fillB<<<NBK, 256, 0, stream>>>(stage, rp2, eb);

    int aggBlocks = NN / 4;
    int gemmBlocks = (NN + 63) / 64;   // 782

    // layer 0: Xb -> Mb -> Hb (relu, bf16)
    k_agg<<<aggBlocks, 256, 0, stream>>>((const uint4*)Xb, rp2, eb, nsrc, ndst, coeff0, (uint2*)Mb);
    k_gemm<128, true><<<gemmBlocks, 256, 0, stream>>>((const unsigned short*)Mb, Bt0, Hb);
    // layer 1
    k_agg<<<aggBlocks, 256, 0, stream>>>((const uint4*)Hb, rp2, eb, nsrc, ndst, coeff1, (uint2*)Mb);
    k_gemm<128, true><<<gemmBlocks, 256, 0, stream>>>((const unsigned short*)Mb, Bt1, Hb);
    // layer 2: final, fp32 out, no relu
    k_agg<<<aggBlocks, 256, 0, stream>>>((const uint4*)Hb, rp2, eb, nsrc, ndst, coeff2, (uint2*)Mb);
    k_gemm<64, false><<<gemmBlocks, 256, 0, stream>>>((const unsigned short*)Mb, Bt2, out);
}